// Round 14
// baseline (215.981 us; speedup 1.0000x reference)
//
#include <hip/hip_runtime.h>
#include <hip/hip_bf16.h>
#include <math.h>

// MP Attention: b=2, n=2048, dim=1024, h=16, d=64.
//  1. prep_inputs: xb=bf16(x) | wn=bf16(w/(max(||row||,eps)*32)) | memkv + pads.
//  2. gemm_qkv:  TRIPLE-BUFFERED 64x128 bf16 MFMA GEMM + pixel-norm epilogue ->
//     Qb (x log2e), Kb rows 4.., Vt transposed. 1536 blocks = 6/CU for the
//     latency-bound K=1024 shape (R13 was 128x128 @ 3/CU).
//  3. attn_mfma: R8/R13 transposed-schedule flash attention (best: 64us):
//     4 waves x 32 q-rows, async16 dbuf K/V staging, S^T=K·Q^T / O^T=V^T·P^T,
//     P^T via wave-private LDS, fixed-shift exp2 softmax.
//  4. gemm_mfma<64,64> depth-3: out = attnb @ wn_out^T + MP residual.

#define EPSN 1e-4f
#define NKEY 2112
#define LOG2E 1.4426950408889634f

typedef __attribute__((ext_vector_type(8))) short short8;
typedef __attribute__((ext_vector_type(4))) short short4v;
typedef __attribute__((ext_vector_type(4))) float floatx4;

typedef __attribute__((address_space(1))) const void g_void;
typedef __attribute__((address_space(3))) void lds_void;

__device__ __forceinline__ void async16(void* lds, const void* g) {
    __builtin_amdgcn_global_load_lds((g_void*)g, (lds_void*)lds, 16, 0, 0);
}

__device__ __forceinline__ short f2bf(float f) {   // RNE
    union { float f; unsigned u; } c{f};
    unsigned r = (c.u + 0x7FFF + ((c.u >> 16) & 1)) >> 16;
    return (short)r;
}
__device__ __forceinline__ short f2bf_fast(float f) {  // round-half-up (P in [0,1])
    union { float f; unsigned u; } c{f};
    return (short)((c.u + 0x8000) >> 16);
}

// Fused setup: cast x, normalize both weight matrices, memkv rows + zero pads.
__global__ __launch_bounds__(256) void prep_inputs(const float* __restrict__ x,
                                                   const float* __restrict__ w_qkv,
                                                   const float* __restrict__ w_out,
                                                   const float* __restrict__ memkv,
                                                   short* __restrict__ xb,
                                                   short* __restrict__ wnqkv,
                                                   short* __restrict__ wnout,
                                                   short* __restrict__ Kb,
                                                   short* __restrict__ Vt) {
    const int bid = blockIdx.x, tid = threadIdx.x;
    if (bid < 4096) {                       // cast x -> bf16
        int i = bid * 1024 + tid * 4;
        float4 v = *(const float4*)(x + i);
        short4v s = {f2bf(v.x), f2bf(v.y), f2bf(v.z), f2bf(v.w)};
        *(short4v*)(xb + i) = s;
        return;
    }
    if (bid < 8192) {                       // weight row norms
        const float* w; short* wn; int r;
        if (bid < 7168) { w = w_qkv; wn = wnqkv; r = bid - 4096; }
        else            { w = w_out; wn = wnout; r = bid - 7168; }
        __shared__ float red[256];
        const float* row = w + (size_t)r * 1024;
        float ss = 0.f;
        for (int c = tid; c < 1024; c += 256) { float v = row[c]; ss += v * v; }
        red[tid] = ss;
        __syncthreads();
        for (int s = 128; s > 0; s >>= 1) {
            if (tid < s) red[tid] += red[tid + s];
            __syncthreads();
        }
        float f = 1.0f / (fmaxf(sqrtf(red[0]), EPSN) * 32.0f);
        for (int c = tid; c < 1024; c += 256) wn[(size_t)r * 1024 + c] = f2bf(row[c] * f);
        return;
    }
    // memkv rows 0..3 of Kb / cols 0..3 of Vt, plus zero pads. One block per bh.
    const int bh = bid - 8192, h = bh & 15;
    const int r = tid >> 2, part = tid & 3;
    if (r < 4) {
        const float* pk = memkv + (size_t)(h * 4 + r) * 64 + part * 16;
        const float* pv = memkv + (size_t)((16 + h) * 4 + r) * 64 + part * 16;
        float k[16], v[16]; float ssk = 0.f, ssv = 0.f;
        #pragma unroll
        for (int i = 0; i < 16; i += 4) {
            float4 a = *(const float4*)(pk + i);
            float4 b = *(const float4*)(pv + i);
            k[i]=a.x; k[i+1]=a.y; k[i+2]=a.z; k[i+3]=a.w;
            v[i]=b.x; v[i+1]=b.y; v[i+2]=b.z; v[i+3]=b.w;
            ssk += a.x*a.x + a.y*a.y + a.z*a.z + a.w*a.w;
            ssv += b.x*b.x + b.y*b.y + b.z*b.z + b.w*b.w;
        }
        ssk += __shfl_xor(ssk, 1); ssk += __shfl_xor(ssk, 2);
        ssv += __shfl_xor(ssv, 1); ssv += __shfl_xor(ssv, 2);
        const float fk = 8.0f / fmaxf(sqrtf(ssk), EPSN);
        const float fv = 8.0f / fmaxf(sqrtf(ssv), EPSN);
        short* kd = Kb + ((size_t)bh * NKEY + r) * 64 + part * 16;
        #pragma unroll
        for (int i = 0; i < 16; i++) kd[i] = f2bf(k[i] * fk);
        #pragma unroll
        for (int i = 0; i < 16; i++)
            Vt[((size_t)bh * 64 + part * 16 + i) * NKEY + r] = f2bf(v[i] * fv);
    }
    for (int p = tid; p < 480; p += 256)
        *(short8*)(Kb + ((size_t)bh * NKEY + 2052) * 64 + p * 8) = (short8){0,0,0,0,0,0,0,0};
    for (int p = tid; p < 960; p += 256) {
        int row = p / 15, c = p % 15;
        *(short4v*)(Vt + ((size_t)bh * 64 + row) * NKEY + 2052 + c * 4) = (short4v){0,0,0,0};
    }
}

// qkv projection GEMM (M=4096, N=3072, K=1024), 64x128 tile, triple-buffered,
// fused pixel-norm epilogue. Wave tile = 32 rows x 64 cols (one head).
__global__ __launch_bounds__(256) void gemm_qkv(const short* __restrict__ A,
                                                const short* __restrict__ B,
                                                short* __restrict__ Qb,
                                                short* __restrict__ Kb,
                                                short* __restrict__ Vt) {
    constexpr int K = 1024;
    __shared__ __align__(16) short As[3][64 * 32];    // 12 KB
    __shared__ __align__(16) short Bs[3][128 * 32];   // 24 KB
    const int tid = threadIdx.x;
    const int wv = tid >> 6, lane = tid & 63;
    const int l16 = lane & 15, quad = lane >> 4;
    const int wr = wv >> 1, wc = wv & 1;
    const int bm0 = blockIdx.y * 64, bn0 = blockIdx.x * 128;
    const int grow = lane >> 2;
    const int gk = (lane & 3) * 8;

    floatx4 acc[2][4];
    #pragma unroll
    for (int i = 0; i < 2; i++)
        #pragma unroll
        for (int j = 0; j < 4; j++) acc[i][j] = (floatx4){0.f, 0.f, 0.f, 0.f};

    const short* Abase = A + (size_t)(bm0 + wv * 16 + grow) * K + gk;
    const short* Bbase = B + (size_t)(bn0 + wv * 32 + grow) * K + gk;

    auto issue = [&](int t, int buf) {
        const int off = t * 32;
        async16(&As[buf][(wv * 16) * 32], Abase + off);
        #pragma unroll
        for (int j = 0; j < 2; j++)
            async16(&Bs[buf][(wv * 32 + j * 16) * 32], Bbase + (size_t)(j * 16) * K + off);
    };
    issue(0, 0);
    issue(1, 1);

    const int NKI = K >> 5;       // 32
    int cur = 0;
    for (int ki = 0; ki < NKI; ki++) {
        if (ki + 2 < NKI) {
            int pre = cur + 2; if (pre >= 3) pre -= 3;
            issue(ki + 2, pre);
            asm volatile("s_waitcnt vmcnt(6)" ::: "memory");  // drain tile ki (3/wave)
        } else if (ki + 1 < NKI) {
            asm volatile("s_waitcnt vmcnt(3)" ::: "memory");
        } else {
            asm volatile("s_waitcnt vmcnt(0)" ::: "memory");
        }
        asm volatile("s_barrier" ::: "memory");
        short8 aA[2], bB[4];
        #pragma unroll
        for (int i = 0; i < 2; i++)
            aA[i] = *(const short8*)&As[cur][(wr * 32 + i * 16 + l16) * 32 + quad * 8];
        #pragma unroll
        for (int j = 0; j < 4; j++)
            bB[j] = *(const short8*)&Bs[cur][(wc * 64 + j * 16 + l16) * 32 + quad * 8];
        #pragma unroll
        for (int i = 0; i < 2; i++)
            #pragma unroll
            for (int j = 0; j < 4; j++)
                acc[i][j] = __builtin_amdgcn_mfma_f32_16x16x32_bf16(aA[i], bB[j], acc[i][j], 0, 0, 0);
        asm volatile("s_barrier" ::: "memory");
        cur = (cur == 2) ? 0 : cur + 1;
    }

    // ---- pixel-norm epilogue: this wave's 64 cols = one head of q/k/v
    const int colbase = bn0 + wc * 64;
    const int which = colbase >> 10;          // 0=q 1=k 2=v
    const int h = (colbase >> 6) & 15;
    float sc[2][4];
    #pragma unroll
    for (int i = 0; i < 2; i++)
        #pragma unroll
        for (int r = 0; r < 4; r++) {
            float ss = 0.f;
            #pragma unroll
            for (int j = 0; j < 4; j++) ss += acc[i][j][r] * acc[i][j][r];
            ss += __shfl_xor(ss, 1); ss += __shfl_xor(ss, 2);
            ss += __shfl_xor(ss, 4); ss += __shfl_xor(ss, 8);
            const float num = (which == 0) ? LOG2E : 8.0f;
            sc[i][r] = num / fmaxf(sqrtf(ss), EPSN);
        }
    if (which == 2) {
        #pragma unroll
        for (int i = 0; i < 2; i++) {
            const int row0 = bm0 + wr * 32 + i * 16 + quad * 4;
            const int bh = (row0 >> 11) * 16 + h;
            const int tok0 = row0 & 2047;
            #pragma unroll
            for (int j = 0; j < 4; j++) {
                const int d = j * 16 + l16;
                short4v o = {f2bf(acc[i][j][0] * sc[i][0]), f2bf(acc[i][j][1] * sc[i][1]),
                             f2bf(acc[i][j][2] * sc[i][2]), f2bf(acc[i][j][3] * sc[i][3])};
                *(short4v*)(Vt + ((size_t)bh * 64 + d) * NKEY + 4 + tok0) = o;
            }
        }
    } else {
        #pragma unroll
        for (int i = 0; i < 2; i++)
            #pragma unroll
            for (int r = 0; r < 4; r++) {
                const int row = bm0 + wr * 32 + i * 16 + quad * 4 + r;
                const int bh = (row >> 11) * 16 + h;
                const int tok = row & 2047;
                const size_t base = (which == 0) ? ((size_t)bh * 2048 + tok) * 64
                                                 : ((size_t)bh * NKEY + 4 + tok) * 64;
                short* dst = (which == 0) ? Qb : Kb;
                #pragma unroll
                for (int j = 0; j < 4; j++)
                    dst[base + j * 16 + l16] = f2bf(acc[i][j][r] * sc[i][r]);
            }
    }
}

// out-projection GEMM, triple-buffered, fp32 out + MP residual.
template<int MT, int NT>
__global__ __launch_bounds__(256) void gemm_mfma(const short* __restrict__ A,
                                                 const short* __restrict__ B,
                                                 float* __restrict__ C,
                                                 int M, int N, int K,
                                                 const float* __restrict__ resid) {
    constexpr int FI = MT / 32;
    constexpr int FJ = NT / 32;
    constexpr int nA = MT / 64;
    constexpr int nB = NT / 64;
    constexpr int NL = nA + nB;
    __shared__ __align__(16) short As[3][MT * 32];
    __shared__ __align__(16) short Bs[3][NT * 32];
    const int tid = threadIdx.x;
    const int wv = tid >> 6, lane = tid & 63;
    const int l16 = lane & 15, quad = lane >> 4;
    const int wr = wv >> 1, wc = wv & 1;
    const int bm0 = blockIdx.y * MT, bn0 = blockIdx.x * NT;
    const int grow = lane >> 2;
    const int gk = (lane & 3) * 8;

    floatx4 acc[FI][FJ];
    #pragma unroll
    for (int i = 0; i < FI; i++)
        #pragma unroll
        for (int j = 0; j < FJ; j++) acc[i][j] = (floatx4){0.f, 0.f, 0.f, 0.f};

    const short* Abase = A + (size_t)(bm0 + wv * (MT / 4) + grow) * K + gk;
    const short* Bbase = B + (size_t)(bn0 + wv * (NT / 4) + grow) * K + gk;

    auto issue = [&](int t, int buf) {
        const int off = t * 32;
        #pragma unroll
        for (int j = 0; j < nA; j++)
            async16(&As[buf][(wv * (MT / 4) + j * 16) * 32], Abase + (size_t)(j * 16) * K + off);
        #pragma unroll
        for (int j = 0; j < nB; j++)
            async16(&Bs[buf][(wv * (NT / 4) + j * 16) * 32], Bbase + (size_t)(j * 16) * K + off);
    };
    issue(0, 0);
    issue(1, 1);

    const int NKI = K >> 5;
    int cur = 0;
    for (int ki = 0; ki < NKI; ki++) {
        if (ki + 2 < NKI) {
            int pre = cur + 2; if (pre >= 3) pre -= 3;
            issue(ki + 2, pre);
            if constexpr (NL == 4)      asm volatile("s_waitcnt vmcnt(8)" ::: "memory");
            else if constexpr (NL == 3) asm volatile("s_waitcnt vmcnt(6)" ::: "memory");
            else                        asm volatile("s_waitcnt vmcnt(4)" ::: "memory");
        } else if (ki + 1 < NKI) {
            if constexpr (NL == 4)      asm volatile("s_waitcnt vmcnt(4)" ::: "memory");
            else if constexpr (NL == 3) asm volatile("s_waitcnt vmcnt(3)" ::: "memory");
            else                        asm volatile("s_waitcnt vmcnt(2)" ::: "memory");
        } else {
            asm volatile("s_waitcnt vmcnt(0)" ::: "memory");
        }
        asm volatile("s_barrier" ::: "memory");
        short8 aA[FI], bB[FJ];
        #pragma unroll
        for (int i = 0; i < FI; i++)
            aA[i] = *(const short8*)&As[cur][(wr * (MT / 2) + i * 16 + l16) * 32 + quad * 8];
        #pragma unroll
        for (int j = 0; j < FJ; j++)
            bB[j] = *(const short8*)&Bs[cur][(wc * (NT / 2) + j * 16 + l16) * 32 + quad * 8];
        #pragma unroll
        for (int i = 0; i < FI; i++)
            #pragma unroll
            for (int j = 0; j < FJ; j++)
                acc[i][j] = __builtin_amdgcn_mfma_f32_16x16x32_bf16(aA[i], bB[j], acc[i][j], 0, 0, 0);
        asm volatile("s_barrier" ::: "memory");
        cur = (cur == 2) ? 0 : cur + 1;
    }
    #pragma unroll
    for (int i = 0; i < FI; i++)
        #pragma unroll
        for (int j = 0; j < FJ; j++)
            #pragma unroll
            for (int r = 0; r < 4; r++) {
                const int row = bm0 + wr * (MT / 2) + i * 16 + quad * 4 + r;
                const int col = bn0 + wc * (NT / 2) + j * 16 + l16;
                const size_t idx = (size_t)row * N + col;
                float v = acc[i][j][r];
                if (resid) v = (v * 0.7f + resid[idx] * 0.3f) * 1.3130643285972254f;
                C[idx] = v;
            }
}

// Flash attention (R8/R13 structure, best measured): 256 thr = 4 waves x 32 q-rows.
// S^T = K·Q^T (A=K frag, B=Q frag) -> C[key][q]; P^T spilled to wave-private
// LDS in [q][key] B-layout; O^T = V^T·P^T. async16 double-buffered staging,
// fixed-shift exp2 softmax, denominator deferred to epilogue.
__global__ __launch_bounds__(256) void attn_mfma(const short* __restrict__ Qb,
                                                 const short* __restrict__ Kb,
                                                 const short* __restrict__ Vt,
                                                 short* __restrict__ out) {
    const int bh = blockIdx.x;
    const int q0 = blockIdx.y * 128;
    const int tid = threadIdx.x;
    const int wave = tid >> 6, lane = tid & 63;
    const int l16 = lane & 15, quad = lane >> 4;

    __shared__ __align__(16) short Ks2[2][2][64 * 32];  // [buf][d-half][key][32]
    __shared__ __align__(16) short Vs2[2][2][64 * 32];  // [buf][key-half][d][32]
    __shared__ __align__(16) short Pw[4][32 * 72];      // per-wave P^T [q][key]

    // Q B-fragments: rows q0 + wave*32 + qg*16 + l16, k-halves
    const short* qbase = Qb + ((size_t)bh * 2048 + q0 + wave * 32 + l16) * 64;
    short8 bQ[2][2];
    #pragma unroll
    for (int qg = 0; qg < 2; qg++)
        #pragma unroll
        for (int dh = 0; dh < 2; dh++)
            bQ[qg][dh] = *(const short8*)(qbase + qg * 1024 + dh * 32 + quad * 8);
    asm volatile("s_waitcnt vmcnt(0)" ::: "memory");   // Q resident before pipeline

    const int grow = lane >> 2, gsub = (lane & 3) * 8;
    auto issue = [&](int tile, int buf) {
        #pragma unroll
        for (int s = 0; s < 4; s++) {
            const int u = wave * 4 + s;        // wave-uniform
            if (u < 8) {
                const int dh = u >> 2, kc = u & 3;
                async16(&Ks2[buf][dh][kc * 512],
                        Kb + ((size_t)bh * NKEY + tile * 64 + kc * 16 + grow) * 64 + dh * 32 + gsub);
            } else {
                const int v = u - 8;
                const int kh = v >> 2, dc = v & 3;
                async16(&Vs2[buf][kh][dc * 512],
                        Vt + ((size_t)bh * 64 + dc * 16 + grow) * NKEY + tile * 64 + kh * 32 + gsub);
            }
        }
    };

    floatx4 O[4][2];   // [d-tile][q-group]
    #pragma unroll
    for (int dt = 0; dt < 4; dt++)
        #pragma unroll
        for (int qg = 0; qg < 2; qg++) O[dt][qg] = (floatx4){0.f, 0.f, 0.f, 0.f};
    float lp[2] = {0.f, 0.f};

    issue(0, 0);
    for (int tile = 0; tile < 33; tile++) {
        const int cur = tile & 1;
        if (tile < 32) {
            issue(tile + 1, cur ^ 1);
            asm volatile("s_waitcnt vmcnt(4)" ::: "memory");
        } else {
            asm volatile("s_waitcnt vmcnt(0)" ::: "memory");
        }
        asm volatile("s_barrier" ::: "memory");

        // ---- S^T = K·Q^T : C[key=quad*4+r][q=l16] per (kt, qg)
        floatx4 S[4][2];
        #pragma unroll
        for (int kt = 0; kt < 4; kt++) {
            short8 aK0 = *(const short8*)&Ks2[cur][0][(kt * 16 + l16) * 32 + quad * 8];
            short8 aK1 = *(const short8*)&Ks2[cur][1][(kt * 16 + l16) * 32 + quad * 8];
            #pragma unroll
            for (int qg = 0; qg < 2; qg++) {
                floatx4 s = (floatx4){-12.f, -12.f, -12.f, -12.f};
                s = __builtin_amdgcn_mfma_f32_16x16x32_bf16(aK0, bQ[qg][0], s, 0, 0, 0);
                s = __builtin_amdgcn_mfma_f32_16x16x32_bf16(aK1, bQ[qg][1], s, 0, 0, 0);
                S[kt][qg] = s;
            }
        }
        if (tile == 32) {   // valid keys: key_local < 4  <=>  kt==0 && quad==0
            #pragma unroll
            for (int kt = 0; kt < 4; kt++)
                #pragma unroll
                for (int qg = 0; qg < 2; qg++)
                    if (kt > 0 || quad > 0)
                        S[kt][qg] = (floatx4){-1e30f, -1e30f, -1e30f, -1e30f};
        }
        // ---- exp2, accumulate denominator, spill P^T in B-layout
        #pragma unroll
        for (int kt = 0; kt < 4; kt++)
            #pragma unroll
            for (int qg = 0; qg < 2; qg++) {
                float p0 = __builtin_amdgcn_exp2f(S[kt][qg][0]);
                float p1 = __builtin_amdgcn_exp2f(S[kt][qg][1]);
                float p2 = __builtin_amdgcn_exp2f(S[kt][qg][2]);
                float p3 = __builtin_amdgcn_exp2f(S[kt][qg][3]);
                lp[qg] += (p0 + p1) + (p2 + p3);
                short4v pk = {f2bf_fast(p0), f2bf_fast(p1), f2bf_fast(p2), f2bf_fast(p3)};
                *(short4v*)&Pw[wave][(qg * 16 + l16) * 72 + kt * 16 + quad * 4] = pk;
            }
        // ---- O^T += V^T·P^T
        short8 bP[2][2];
        #pragma unroll
        for (int qg = 0; qg < 2; qg++)
            #pragma unroll
            for (int kh = 0; kh < 2; kh++)
                bP[qg][kh] = *(const short8*)&Pw[wave][(qg * 16 + l16) * 72 + kh * 32 + quad * 8];
        #pragma unroll
        for (int dt = 0; dt < 4; dt++) {
            short8 aV0 = *(const short8*)&Vs2[cur][0][(dt * 16 + l16) * 32 + quad * 8];
            short8 aV1 = *(const short8*)&Vs2[cur][1][(dt * 16 + l16) * 32 + quad * 8];
            #pragma unroll
            for (int qg = 0; qg < 2; qg++) {
                O[dt][qg] = __builtin_amdgcn_mfma_f32_16x16x32_bf16(aV0, bP[qg][0], O[dt][qg], 0, 0, 0);
                O[dt][qg] = __builtin_amdgcn_mfma_f32_16x16x32_bf16(aV1, bP[qg][1], O[dt][qg], 0, 0, 0);
            }
        }
        asm volatile("s_barrier" ::: "memory");
    }

    // ---- epilogue: reduce denominator across quads, scale, store transposed
    const int bb = bh >> 4, h = bh & 15;
    float inv[2];
    #pragma unroll
    for (int qg = 0; qg < 2; qg++) {
        float l = lp[qg];
        l += __shfl_xor(l, 16);
        l += __shfl_xor(l, 32);
        inv[qg] = 1.0f / l;
    }
    #pragma unroll
    for (int dt = 0; dt < 4; dt++)
        #pragma unroll
        for (int qg = 0; qg < 2; qg++) {
            const int token = q0 + wave * 32 + qg * 16 + l16;
            short4v o = {f2bf(O[dt][qg][0] * inv[qg]), f2bf(O[dt][qg][1] * inv[qg]),
                         f2bf(O[dt][qg][2] * inv[qg]), f2bf(O[dt][qg][3] * inv[qg])};
            *(short4v*)(out + ((size_t)(bb * 2048 + token)) * 1024 + h * 64 + dt * 16 + quad * 4) = o;
        }
}

extern "C" void kernel_launch(void* const* d_in, const int* in_sizes, int n_in,
                              void* d_out, int out_size, void* d_ws, size_t ws_size,
                              hipStream_t stream) {
    const float* x      = (const float*)d_in[0];
    const float* w_qkv  = (const float*)d_in[1];
    const float* w_out  = (const float*)d_in[2];
    const float* mem_kv = (const float*)d_in[3];
    float* out = (float*)d_out;

    char* ws = (char*)d_ws;
    short* wnqkv_b = (short*)(ws);                    // 6 MB
    short* wnout_b = (short*)(ws + (6u << 20));       // 2 MB
    short* xb      = (short*)(ws + (8u << 20));       // 8 MB
    short* Qb      = (short*)(ws + (16u << 20));      // 8 MB
    short* Kb      = (short*)(ws + (24u << 20));      // 8.25 MB
    short* Vt      = (short*)(ws + (33u << 20));      // 8.25 MB
    short* attnb   = (short*)(ws + (42u << 20));      // 8 MB  (total ~50 MB)

    prep_inputs<<<8224, 256, 0, stream>>>(x, w_qkv, w_out, mem_kv,
                                          xb, wnqkv_b, wnout_b, Kb, Vt);

    // 64x128 tile: grid (24, 64) = 1536 blocks = 6/CU
    gemm_qkv<<<dim3(3072 / 128, 4096 / 64), 256, 0, stream>>>(
        xb, wnqkv_b, Qb, Kb, Vt);

    attn_mfma<<<dim3(32, 16), 256, 0, stream>>>(Qb, Kb, Vt, attnb);

    gemm_mfma<64, 64><<<dim3(1024 / 64, 4096 / 64), 256, 0, stream>>>(
        attnb, wnout_b, out, 4096, 1024, 1024, x);
}

// Round 15
// 205.120 us; speedup vs baseline: 1.0529x; 1.0529x over previous
//
#include <hip/hip_runtime.h>
#include <hip/hip_bf16.h>
#include <math.h>

// MP Attention: b=2, n=2048, dim=1024, h=16, d=64.
//  1. prep_inputs: xb=bf16(x) | wn=bf16(w/(max(||row||,eps)*32)) | memkv + pads.
//  2. gemm_qkv:  R13's triple-buffered 128x128 bf16 MFMA GEMM + pixel-norm
//     epilogue -> Qb (x log2e), Kb rows 4.., Vt transposed. (R14's 64x128
//     retile regressed: fewer MFMAs per barrier interval.)
//  3. attn_mfma: transposed-schedule flash attention, now with TRIPLE-buffered
//     K/V staging at prefetch distance 1 and a SINGLE barrier per tile
//     (buffer (t+1)%3's readers are provably past barrier(t-1)).
//  4. gemm_mfma<64,64> depth-3: out = attnb @ wn_out^T + MP residual.

#define EPSN 1e-4f
#define NKEY 2112
#define LOG2E 1.4426950408889634f

typedef __attribute__((ext_vector_type(8))) short short8;
typedef __attribute__((ext_vector_type(4))) short short4v;
typedef __attribute__((ext_vector_type(4))) float floatx4;

typedef __attribute__((address_space(1))) const void g_void;
typedef __attribute__((address_space(3))) void lds_void;

__device__ __forceinline__ void async16(void* lds, const void* g) {
    __builtin_amdgcn_global_load_lds((g_void*)g, (lds_void*)lds, 16, 0, 0);
}

__device__ __forceinline__ short f2bf(float f) {   // RNE
    union { float f; unsigned u; } c{f};
    unsigned r = (c.u + 0x7FFF + ((c.u >> 16) & 1)) >> 16;
    return (short)r;
}
__device__ __forceinline__ short f2bf_fast(float f) {  // round-half-up (P in [0,1])
    union { float f; unsigned u; } c{f};
    return (short)((c.u + 0x8000) >> 16);
}

// Fused setup: cast x, normalize both weight matrices, memkv rows + zero pads.
__global__ __launch_bounds__(256) void prep_inputs(const float* __restrict__ x,
                                                   const float* __restrict__ w_qkv,
                                                   const float* __restrict__ w_out,
                                                   const float* __restrict__ memkv,
                                                   short* __restrict__ xb,
                                                   short* __restrict__ wnqkv,
                                                   short* __restrict__ wnout,
                                                   short* __restrict__ Kb,
                                                   short* __restrict__ Vt) {
    const int bid = blockIdx.x, tid = threadIdx.x;
    if (bid < 4096) {                       // cast x -> bf16
        int i = bid * 1024 + tid * 4;
        float4 v = *(const float4*)(x + i);
        short4v s = {f2bf(v.x), f2bf(v.y), f2bf(v.z), f2bf(v.w)};
        *(short4v*)(xb + i) = s;
        return;
    }
    if (bid < 8192) {                       // weight row norms
        const float* w; short* wn; int r;
        if (bid < 7168) { w = w_qkv; wn = wnqkv; r = bid - 4096; }
        else            { w = w_out; wn = wnout; r = bid - 7168; }
        __shared__ float red[256];
        const float* row = w + (size_t)r * 1024;
        float ss = 0.f;
        for (int c = tid; c < 1024; c += 256) { float v = row[c]; ss += v * v; }
        red[tid] = ss;
        __syncthreads();
        for (int s = 128; s > 0; s >>= 1) {
            if (tid < s) red[tid] += red[tid + s];
            __syncthreads();
        }
        float f = 1.0f / (fmaxf(sqrtf(red[0]), EPSN) * 32.0f);
        for (int c = tid; c < 1024; c += 256) wn[(size_t)r * 1024 + c] = f2bf(row[c] * f);
        return;
    }
    // memkv rows 0..3 of Kb / cols 0..3 of Vt, plus zero pads. One block per bh.
    const int bh = bid - 8192, h = bh & 15;
    const int r = tid >> 2, part = tid & 3;
    if (r < 4) {
        const float* pk = memkv + (size_t)(h * 4 + r) * 64 + part * 16;
        const float* pv = memkv + (size_t)((16 + h) * 4 + r) * 64 + part * 16;
        float k[16], v[16]; float ssk = 0.f, ssv = 0.f;
        #pragma unroll
        for (int i = 0; i < 16; i += 4) {
            float4 a = *(const float4*)(pk + i);
            float4 b = *(const float4*)(pv + i);
            k[i]=a.x; k[i+1]=a.y; k[i+2]=a.z; k[i+3]=a.w;
            v[i]=b.x; v[i+1]=b.y; v[i+2]=b.z; v[i+3]=b.w;
            ssk += a.x*a.x + a.y*a.y + a.z*a.z + a.w*a.w;
            ssv += b.x*b.x + b.y*b.y + b.z*b.z + b.w*b.w;
        }
        ssk += __shfl_xor(ssk, 1); ssk += __shfl_xor(ssk, 2);
        ssv += __shfl_xor(ssv, 1); ssv += __shfl_xor(ssv, 2);
        const float fk = 8.0f / fmaxf(sqrtf(ssk), EPSN);
        const float fv = 8.0f / fmaxf(sqrtf(ssv), EPSN);
        short* kd = Kb + ((size_t)bh * NKEY + r) * 64 + part * 16;
        #pragma unroll
        for (int i = 0; i < 16; i++) kd[i] = f2bf(k[i] * fk);
        #pragma unroll
        for (int i = 0; i < 16; i++)
            Vt[((size_t)bh * 64 + part * 16 + i) * NKEY + r] = f2bf(v[i] * fv);
    }
    for (int p = tid; p < 480; p += 256)
        *(short8*)(Kb + ((size_t)bh * NKEY + 2052) * 64 + p * 8) = (short8){0,0,0,0,0,0,0,0};
    for (int p = tid; p < 960; p += 256) {
        int row = p / 15, c = p % 15;
        *(short4v*)(Vt + ((size_t)bh * 64 + row) * NKEY + 2052 + c * 4) = (short4v){0,0,0,0};
    }
}

// qkv projection GEMM (M=4096, N=3072, K=1024), 128x128 tile, triple-buffered,
// fused pixel-norm epilogue (R13's best-measured configuration).
__global__ __launch_bounds__(256) void gemm_qkv(const short* __restrict__ A,
                                                const short* __restrict__ B,
                                                short* __restrict__ Qb,
                                                short* __restrict__ Kb,
                                                short* __restrict__ Vt) {
    constexpr int K = 1024;
    __shared__ __align__(16) short As[3][128 * 32];   // 24 KB
    __shared__ __align__(16) short Bs[3][128 * 32];   // 24 KB
    const int tid = threadIdx.x;
    const int wv = tid >> 6, lane = tid & 63;
    const int l16 = lane & 15, quad = lane >> 4;
    const int wr = wv >> 1, wc = wv & 1;
    const int bm0 = blockIdx.y * 128, bn0 = blockIdx.x * 128;
    const int grow = lane >> 2;
    const int gk = (lane & 3) * 8;

    floatx4 acc[4][4];
    #pragma unroll
    for (int i = 0; i < 4; i++)
        #pragma unroll
        for (int j = 0; j < 4; j++) acc[i][j] = (floatx4){0.f, 0.f, 0.f, 0.f};

    const short* Abase = A + (size_t)(bm0 + wv * 32 + grow) * K + gk;
    const short* Bbase = B + (size_t)(bn0 + wv * 32 + grow) * K + gk;

    auto issue = [&](int t, int buf) {
        const int off = t * 32;
        #pragma unroll
        for (int j = 0; j < 2; j++) {
            async16(&As[buf][(wv * 32 + j * 16) * 32], Abase + (size_t)(j * 16) * K + off);
            async16(&Bs[buf][(wv * 32 + j * 16) * 32], Bbase + (size_t)(j * 16) * K + off);
        }
    };
    issue(0, 0);
    issue(1, 1);

    const int NKI = K >> 5;       // 32
    int cur = 0;
    for (int ki = 0; ki < NKI; ki++) {
        if (ki + 2 < NKI) {
            int pre = cur + 2; if (pre >= 3) pre -= 3;
            issue(ki + 2, pre);
            asm volatile("s_waitcnt vmcnt(8)" ::: "memory");  // drain tile ki (4/wave)
        } else if (ki + 1 < NKI) {
            asm volatile("s_waitcnt vmcnt(4)" ::: "memory");
        } else {
            asm volatile("s_waitcnt vmcnt(0)" ::: "memory");
        }
        asm volatile("s_barrier" ::: "memory");
        short8 aA[4], bB[4];
        #pragma unroll
        for (int i = 0; i < 4; i++)
            aA[i] = *(const short8*)&As[cur][(wr * 64 + i * 16 + l16) * 32 + quad * 8];
        #pragma unroll
        for (int j = 0; j < 4; j++)
            bB[j] = *(const short8*)&Bs[cur][(wc * 64 + j * 16 + l16) * 32 + quad * 8];
        #pragma unroll
        for (int i = 0; i < 4; i++)
            #pragma unroll
            for (int j = 0; j < 4; j++)
                acc[i][j] = __builtin_amdgcn_mfma_f32_16x16x32_bf16(aA[i], bB[j], acc[i][j], 0, 0, 0);
        asm volatile("s_barrier" ::: "memory");
        cur = (cur == 2) ? 0 : cur + 1;
    }

    // ---- pixel-norm epilogue: this wave's 64 cols = one head of q/k/v
    const int colbase = bn0 + wc * 64;
    const int which = colbase >> 10;          // 0=q 1=k 2=v
    const int h = (colbase >> 6) & 15;
    float sc[4][4];
    #pragma unroll
    for (int i = 0; i < 4; i++)
        #pragma unroll
        for (int r = 0; r < 4; r++) {
            float ss = 0.f;
            #pragma unroll
            for (int j = 0; j < 4; j++) ss += acc[i][j][r] * acc[i][j][r];
            ss += __shfl_xor(ss, 1); ss += __shfl_xor(ss, 2);
            ss += __shfl_xor(ss, 4); ss += __shfl_xor(ss, 8);
            const float num = (which == 0) ? LOG2E : 8.0f;
            sc[i][r] = num / fmaxf(sqrtf(ss), EPSN);
        }
    if (which == 2) {
        #pragma unroll
        for (int i = 0; i < 4; i++) {
            const int row0 = bm0 + wr * 64 + i * 16 + quad * 4;
            const int bh = (row0 >> 11) * 16 + h;
            const int tok0 = row0 & 2047;
            #pragma unroll
            for (int j = 0; j < 4; j++) {
                const int d = j * 16 + l16;
                short4v o = {f2bf(acc[i][j][0] * sc[i][0]), f2bf(acc[i][j][1] * sc[i][1]),
                             f2bf(acc[i][j][2] * sc[i][2]), f2bf(acc[i][j][3] * sc[i][3])};
                *(short4v*)(Vt + ((size_t)bh * 64 + d) * NKEY + 4 + tok0) = o;
            }
        }
    } else {
        #pragma unroll
        for (int i = 0; i < 4; i++)
            #pragma unroll
            for (int r = 0; r < 4; r++) {
                const int row = bm0 + wr * 64 + i * 16 + quad * 4 + r;
                const int bh = (row >> 11) * 16 + h;
                const int tok = row & 2047;
                const size_t base = (which == 0) ? ((size_t)bh * 2048 + tok) * 64
                                                 : ((size_t)bh * NKEY + 4 + tok) * 64;
                short* dst = (which == 0) ? Qb : Kb;
                #pragma unroll
                for (int j = 0; j < 4; j++)
                    dst[base + j * 16 + l16] = f2bf(acc[i][j][r] * sc[i][r]);
            }
    }
}

// out-projection GEMM, triple-buffered, fp32 out + MP residual.
template<int MT, int NT>
__global__ __launch_bounds__(256) void gemm_mfma(const short* __restrict__ A,
                                                 const short* __restrict__ B,
                                                 float* __restrict__ C,
                                                 int M, int N, int K,
                                                 const float* __restrict__ resid) {
    constexpr int FI = MT / 32;
    constexpr int FJ = NT / 32;
    constexpr int nA = MT / 64;
    constexpr int nB = NT / 64;
    constexpr int NL = nA + nB;
    __shared__ __align__(16) short As[3][MT * 32];
    __shared__ __align__(16) short Bs[3][NT * 32];
    const int tid = threadIdx.x;
    const int wv = tid >> 6, lane = tid & 63;
    const int l16 = lane & 15, quad = lane >> 4;
    const int wr = wv >> 1, wc = wv & 1;
    const int bm0 = blockIdx.y * MT, bn0 = blockIdx.x * NT;
    const int grow = lane >> 2;
    const int gk = (lane & 3) * 8;

    floatx4 acc[FI][FJ];
    #pragma unroll
    for (int i = 0; i < FI; i++)
        #pragma unroll
        for (int j = 0; j < FJ; j++) acc[i][j] = (floatx4){0.f, 0.f, 0.f, 0.f};

    const short* Abase = A + (size_t)(bm0 + wv * (MT / 4) + grow) * K + gk;
    const short* Bbase = B + (size_t)(bn0 + wv * (NT / 4) + grow) * K + gk;

    auto issue = [&](int t, int buf) {
        const int off = t * 32;
        #pragma unroll
        for (int j = 0; j < nA; j++)
            async16(&As[buf][(wv * (MT / 4) + j * 16) * 32], Abase + (size_t)(j * 16) * K + off);
        #pragma unroll
        for (int j = 0; j < nB; j++)
            async16(&Bs[buf][(wv * (NT / 4) + j * 16) * 32], Bbase + (size_t)(j * 16) * K + off);
    };
    issue(0, 0);
    issue(1, 1);

    const int NKI = K >> 5;
    int cur = 0;
    for (int ki = 0; ki < NKI; ki++) {
        if (ki + 2 < NKI) {
            int pre = cur + 2; if (pre >= 3) pre -= 3;
            issue(ki + 2, pre);
            if constexpr (NL == 4)      asm volatile("s_waitcnt vmcnt(8)" ::: "memory");
            else if constexpr (NL == 3) asm volatile("s_waitcnt vmcnt(6)" ::: "memory");
            else                        asm volatile("s_waitcnt vmcnt(4)" ::: "memory");
        } else if (ki + 1 < NKI) {
            if constexpr (NL == 4)      asm volatile("s_waitcnt vmcnt(4)" ::: "memory");
            else if constexpr (NL == 3) asm volatile("s_waitcnt vmcnt(3)" ::: "memory");
            else                        asm volatile("s_waitcnt vmcnt(2)" ::: "memory");
        } else {
            asm volatile("s_waitcnt vmcnt(0)" ::: "memory");
        }
        asm volatile("s_barrier" ::: "memory");
        short8 aA[FI], bB[FJ];
        #pragma unroll
        for (int i = 0; i < FI; i++)
            aA[i] = *(const short8*)&As[cur][(wr * (MT / 2) + i * 16 + l16) * 32 + quad * 8];
        #pragma unroll
        for (int j = 0; j < FJ; j++)
            bB[j] = *(const short8*)&Bs[cur][(wc * (NT / 2) + j * 16 + l16) * 32 + quad * 8];
        #pragma unroll
        for (int i = 0; i < FI; i++)
            #pragma unroll
            for (int j = 0; j < FJ; j++)
                acc[i][j] = __builtin_amdgcn_mfma_f32_16x16x32_bf16(aA[i], bB[j], acc[i][j], 0, 0, 0);
        asm volatile("s_barrier" ::: "memory");
        cur = (cur == 2) ? 0 : cur + 1;
    }
    #pragma unroll
    for (int i = 0; i < FI; i++)
        #pragma unroll
        for (int j = 0; j < FJ; j++)
            #pragma unroll
            for (int r = 0; r < 4; r++) {
                const int row = bm0 + wr * (MT / 2) + i * 16 + quad * 4 + r;
                const int col = bn0 + wc * (NT / 2) + j * 16 + l16;
                const size_t idx = (size_t)row * N + col;
                float v = acc[i][j][r];
                if (resid) v = (v * 0.7f + resid[idx] * 0.3f) * 1.3130643285972254f;
                C[idx] = v;
            }
}

// Flash attention, transposed schedule, 4 waves x 32 q-rows. Now TRIPLE-buffered
// staging at prefetch distance 1 with a SINGLE barrier per tile:
// issue(t+1) targets buf (t+1)%3 = (t-2)%3, whose readers (compute t-2) all
// passed barrier(t-1) before any wave reaches iteration t's issue.
__global__ __launch_bounds__(256) void attn_mfma(const short* __restrict__ Qb,
                                                 const short* __restrict__ Kb,
                                                 const short* __restrict__ Vt,
                                                 short* __restrict__ out) {
    const int bh = blockIdx.x;
    const int q0 = blockIdx.y * 128;
    const int tid = threadIdx.x;
    const int wave = tid >> 6, lane = tid & 63;
    const int l16 = lane & 15, quad = lane >> 4;

    __shared__ __align__(16) short Ks2[3][2][64 * 32];  // [buf][d-half][key][32]
    __shared__ __align__(16) short Vs2[3][2][64 * 32];  // [buf][key-half][d][32]
    __shared__ __align__(16) short Pw[4][32 * 72];      // per-wave P^T [q][key]

    // Q B-fragments: rows q0 + wave*32 + qg*16 + l16, k-halves
    const short* qbase = Qb + ((size_t)bh * 2048 + q0 + wave * 32 + l16) * 64;
    short8 bQ[2][2];
    #pragma unroll
    for (int qg = 0; qg < 2; qg++)
        #pragma unroll
        for (int dh = 0; dh < 2; dh++)
            bQ[qg][dh] = *(const short8*)(qbase + qg * 1024 + dh * 32 + quad * 8);
    asm volatile("s_waitcnt vmcnt(0)" ::: "memory");   // Q resident before pipeline

    const int grow = lane >> 2, gsub = (lane & 3) * 8;
    auto issue = [&](int tile, int buf) {
        #pragma unroll
        for (int s = 0; s < 4; s++) {
            const int u = wave * 4 + s;        // wave-uniform
            if (u < 8) {
                const int dh = u >> 2, kc = u & 3;
                async16(&Ks2[buf][dh][kc * 512],
                        Kb + ((size_t)bh * NKEY + tile * 64 + kc * 16 + grow) * 64 + dh * 32 + gsub);
            } else {
                const int v = u - 8;
                const int kh = v >> 2, dc = v & 3;
                async16(&Vs2[buf][kh][dc * 512],
                        Vt + ((size_t)bh * 64 + dc * 16 + grow) * NKEY + tile * 64 + kh * 32 + gsub);
            }
        }
    };

    floatx4 O[4][2];   // [d-tile][q-group]
    #pragma unroll
    for (int dt = 0; dt < 4; dt++)
        #pragma unroll
        for (int qg = 0; qg < 2; qg++) O[dt][qg] = (floatx4){0.f, 0.f, 0.f, 0.f};
    float lp[2] = {0.f, 0.f};

    issue(0, 0);
    int cur = 0;
    for (int tile = 0; tile < 33; tile++) {
        if (tile < 32) {
            int nxt = cur + 1; if (nxt == 3) nxt = 0;
            issue(tile + 1, nxt);
            asm volatile("s_waitcnt vmcnt(4)" ::: "memory");   // drain tile's 4 loads
        } else {
            asm volatile("s_waitcnt vmcnt(0)" ::: "memory");
        }
        asm volatile("s_barrier" ::: "memory");    // single barrier per tile

        // ---- S^T = K·Q^T : C[key=quad*4+r][q=l16] per (kt, qg)
        floatx4 S[4][2];
        #pragma unroll
        for (int kt = 0; kt < 4; kt++) {
            short8 aK0 = *(const short8*)&Ks2[cur][0][(kt * 16 + l16) * 32 + quad * 8];
            short8 aK1 = *(const short8*)&Ks2[cur][1][(kt * 16 + l16) * 32 + quad * 8];
            #pragma unroll
            for (int qg = 0; qg < 2; qg++) {
                floatx4 s = (floatx4){-12.f, -12.f, -12.f, -12.f};
                s = __builtin_amdgcn_mfma_f32_16x16x32_bf16(aK0, bQ[qg][0], s, 0, 0, 0);
                s = __builtin_amdgcn_mfma_f32_16x16x32_bf16(aK1, bQ[qg][1], s, 0, 0, 0);
                S[kt][qg] = s;
            }
        }
        if (tile == 32) {   // valid keys: key_local < 4  <=>  kt==0 && quad==0
            #pragma unroll
            for (int kt = 0; kt < 4; kt++)
                #pragma unroll
                for (int qg = 0; qg < 2; qg++)
                    if (kt > 0 || quad > 0)
                        S[kt][qg] = (floatx4){-1e30f, -1e30f, -1e30f, -1e30f};
        }
        // ---- exp2, accumulate denominator, spill P^T in B-layout
        #pragma unroll
        for (int kt = 0; kt < 4; kt++)
            #pragma unroll
            for (int qg = 0; qg < 2; qg++) {
                float p0 = __builtin_amdgcn_exp2f(S[kt][qg][0]);
                float p1 = __builtin_amdgcn_exp2f(S[kt][qg][1]);
                float p2 = __builtin_amdgcn_exp2f(S[kt][qg][2]);
                float p3 = __builtin_amdgcn_exp2f(S[kt][qg][3]);
                lp[qg] += (p0 + p1) + (p2 + p3);
                short4v pk = {f2bf_fast(p0), f2bf_fast(p1), f2bf_fast(p2), f2bf_fast(p3)};
                *(short4v*)&Pw[wave][(qg * 16 + l16) * 72 + kt * 16 + quad * 4] = pk;
            }
        // ---- O^T += V^T·P^T
        short8 bP[2][2];
        #pragma unroll
        for (int qg = 0; qg < 2; qg++)
            #pragma unroll
            for (int kh = 0; kh < 2; kh++)
                bP[qg][kh] = *(const short8*)&Pw[wave][(qg * 16 + l16) * 72 + kh * 32 + quad * 8];
        #pragma unroll
        for (int dt = 0; dt < 4; dt++) {
            short8 aV0 = *(const short8*)&Vs2[cur][0][(dt * 16 + l16) * 32 + quad * 8];
            short8 aV1 = *(const short8*)&Vs2[cur][1][(dt * 16 + l16) * 32 + quad * 8];
            #pragma unroll
            for (int qg = 0; qg < 2; qg++) {
                O[dt][qg] = __builtin_amdgcn_mfma_f32_16x16x32_bf16(aV0, bP[qg][0], O[dt][qg], 0, 0, 0);
                O[dt][qg] = __builtin_amdgcn_mfma_f32_16x16x32_bf16(aV1, bP[qg][1], O[dt][qg], 0, 0, 0);
            }
        }
        cur = cur + 1; if (cur == 3) cur = 0;
    }

    // ---- epilogue: reduce denominator across quads, scale, store transposed
    const int bb = bh >> 4, h = bh & 15;
    float inv[2];
    #pragma unroll
    for (int qg = 0; qg < 2; qg++) {
        float l = lp[qg];
        l += __shfl_xor(l, 16);
        l += __shfl_xor(l, 32);
        inv[qg] = 1.0f / l;
    }
    #pragma unroll
    for (int dt = 0; dt < 4; dt++)
        #pragma unroll
        for (int qg = 0; qg < 2; qg++) {
            const int token = q0 + wave * 32 + qg * 16 + l16;
            short4v o = {f2bf(O[dt][qg][0] * inv[qg]), f2bf(O[dt][qg][1] * inv[qg]),
                         f2bf(O[dt][qg][2] * inv[qg]), f2bf(O[dt][qg][3] * inv[qg])};
            *(short4v*)(out + ((size_t)(bb * 2048 + token)) * 1024 + h * 64 + dt * 16 + quad * 4) = o;
        }
}

extern "C" void kernel_launch(void* const* d_in, const int* in_sizes, int n_in,
                              void* d_out, int out_size, void* d_ws, size_t ws_size,
                              hipStream_t stream) {
    const float* x      = (const float*)d_in[0];
    const float* w_qkv  = (const float*)d_in[1];
    const float* w_out  = (const float*)d_in[2];
    const float* mem_kv = (const float*)d_in[3];
    float* out = (float*)d_out;

    char* ws = (char*)d_ws;
    short* wnqkv_b = (short*)(ws);                    // 6 MB
    short* wnout_b = (short*)(ws + (6u << 20));       // 2 MB
    short* xb      = (short*)(ws + (8u << 20));       // 8 MB
    short* Qb      = (short*)(ws + (16u << 20));      // 8 MB
    short* Kb      = (short*)(ws + (24u << 20));      // 8.25 MB
    short* Vt      = (short*)(ws + (33u << 20));      // 8.25 MB
    short* attnb   = (short*)(ws + (42u << 20));      // 8 MB  (total ~50 MB)

    prep_inputs<<<8224, 256, 0, stream>>>(x, w_qkv, w_out, mem_kv,
                                          xb, wnqkv_b, wnout_b, Kb, Vt);

    // 128x128 tile (R13 best): grid (24, 32)
    gemm_qkv<<<dim3(3072 / 128, 4096 / 128), 256, 0, stream>>>(
        xb, wnqkv_b, Qb, Kb, Vt);

    attn_mfma<<<dim3(32, 16), 256, 0, stream>>>(Qb, Kb, Vt, attnb);

    gemm_mfma<64, 64><<<dim3(1024 / 64, 4096 / 64), 256, 0, stream>>>(
        attnb, wnout_b, out, 4096, 1024, 1024, x);
}